// Round 12
// baseline (1322.706 us; speedup 1.0000x reference)
//
#include <hip/hip_runtime.h>
#include <hip/hip_bf16.h>

#define N_PTS 8192
#define NSAMP 1024
#define NGRP  32
#define NTASK (16 * NSAMP)

typedef __attribute__((ext_vector_type(8))) short bf16x8;   // MFMA A/B frag
typedef __attribute__((ext_vector_type(4))) float f32x4;    // MFMA C/D frag

static __device__ inline unsigned short f2bf(float f) {
  __hip_bfloat16 h = __float2bfloat16(f);   // RTNE
  return __builtin_bit_cast(unsigned short, h);
}

// DPP max step: invalid lanes keep 'old' (=r), identity for max.
#define DPP_MAXSTEP(r, ctrl)                                                  \
  r = fmaxf(r, __int_as_float(__builtin_amdgcn_update_dpp(                    \
          __float_as_int(r), __float_as_int(r), (ctrl), 0xf, 0xf, false)))

// ---------------------------------------------------------------------------
// Weight prep — pack W1/W2/W3 into fragment-ordered bf16 records.
//   record(nt,ks)[lane][j] = W[k = 32ks + (lane>>4)*8 + j][n = 16nt + (lane&15)]
// zero-padded k >= K. 1KB/record, lane*16B consecutive -> coalesced loads.
// ---------------------------------------------------------------------------
__global__ __launch_bounds__(256) void prep_w_kernel(
    const float* __restrict__ W1, const float* __restrict__ W2,
    const float* __restrict__ W3, unsigned short* __restrict__ wf1,
    unsigned short* __restrict__ wf2, unsigned short* __restrict__ wf3)
{
  int tid = blockIdx.x * 256 + threadIdx.x;
  int rec = tid >> 6, lane = tid & 63;
  if (rec >= 92) return;
  const float* W; unsigned short* dst; int N, K, ksteps, rl;
  if (rec < 12)      { W = W1; dst = wf1; N = 64;  K = 67;  ksteps = 3; rl = rec; }
  else if (rec < 28) { W = W2; dst = wf2; N = 128; K = 64;  ksteps = 2; rl = rec - 12; }
  else               { W = W3; dst = wf3; N = 256; K = 128; ksteps = 4; rl = rec - 28; }
  int nt = rl / ksteps, ks = rl - nt * ksteps;
  int n  = nt * 16 + (lane & 15);
  int kb = ks * 32 + (lane >> 4) * 8;
  unsigned short v[8] __attribute__((aligned(16)));
  #pragma unroll
  for (int j = 0; j < 8; ++j) {
    int k = kb + j;
    v[j] = f2bf((k < K) ? W[k * N + n] : 0.0f);
  }
  *(uint4*)(dst + ((size_t)rl * 64 + lane) * 8) = *(const uint4*)v;
}

// ---------------------------------------------------------------------------
// Fused persistent kernel. 256 blocks x 512 threads, all resident.
//  blocks 0..15 : FPS producer (exact R7 body, bit-exact — DO NOT TOUCH the
//                 distance math / tie-break) + chunk publisher every 64 iters
//                 (coalesced flush + agent-RELEASE progress bump).
//  blocks 16+   : workers — atomic task queue, spin on progress (RELAXED
//                 poll + one ACQUIRE), ball query (wave 0, bit-exact eager
//                 rounding) -> gather -> bf16-MFMA MLP -> max-pool.
// Coherence surface: workers read ONLY sampled (t0, after ACQUIRE-invalidate)
// among producer-written data; xyz/fea are read-only inputs.
// ---------------------------------------------------------------------------
__global__
__attribute__((amdgpu_flat_work_group_size(512, 512)))
__attribute__((amdgpu_waves_per_eu(2, 2)))
void fused_kernel(
    const float* __restrict__ xyz, const float* __restrict__ fea,
    float* __restrict__ out_sampled, float* __restrict__ out_mlp,
    const unsigned short* __restrict__ wf1, const unsigned short* __restrict__ wf2,
    const unsigned short* __restrict__ wf3, const float* __restrict__ b1,
    const float* __restrict__ b2, const float* __restrict__ b3,
    unsigned* __restrict__ ctrl)   // ctrl[0]=task queue, ctrl[1+b]=progress
{
  #pragma clang fp contract(off)
  const int blk = blockIdx.x;
  const int t = threadIdx.x;

  if (blk < 16) {
    // ================= FPS producer =================
    const int b = blk;
    const float* bx = xyz + (size_t)b * N_PTS * 3;

    float px[16], py[16], pz[16], dist[16];
    {
      const float4* src = (const float4*)(bx + t * 48);
      float4 v0 = src[0], v1 = src[1], v2 = src[2];
      float4 v3 = src[3], v4 = src[4], v5 = src[5];
      float4 v6 = src[6], v7 = src[7], v8 = src[8];
      float4 v9 = src[9], v10 = src[10], v11 = src[11];
      px[ 0]=v0.x; py[ 0]=v0.y; pz[ 0]=v0.z;
      px[ 1]=v0.w; py[ 1]=v1.x; pz[ 1]=v1.y;
      px[ 2]=v1.z; py[ 2]=v1.w; pz[ 2]=v2.x;
      px[ 3]=v2.y; py[ 3]=v2.z; pz[ 3]=v2.w;
      px[ 4]=v3.x; py[ 4]=v3.y; pz[ 4]=v3.z;
      px[ 5]=v3.w; py[ 5]=v4.x; pz[ 5]=v4.y;
      px[ 6]=v4.z; py[ 6]=v4.w; pz[ 6]=v5.x;
      px[ 7]=v5.y; py[ 7]=v5.z; pz[ 7]=v5.w;
      px[ 8]=v6.x; py[ 8]=v6.y; pz[ 8]=v6.z;
      px[ 9]=v6.w; py[ 9]=v7.x; pz[ 9]=v7.y;
      px[10]=v7.z; py[10]=v7.w; pz[10]=v8.x;
      px[11]=v8.y; py[11]=v8.z; pz[11]=v8.w;
      px[12]=v9.x; py[12]=v9.y; pz[12]=v9.z;
      px[13]=v9.w; py[13]=v10.x; pz[13]=v10.y;
      px[14]=v10.z; py[14]=v10.w; pz[14]=v11.x;
      px[15]=v11.y; py[15]=v11.z; pz[15]=v11.w;
    }
    #pragma unroll
    for (int r = 0; r < 16; ++r) dist[r] = 10000000000.0f;

    __shared__ uint2 part[2][8];
    __shared__ float out_lds[NSAMP * 3];

    const int lane = t & 63;
    const int wv   = t >> 6;

    float cx = bx[0], cy = bx[1], cz = bx[2];  // initial centroid = point 0

    for (int it = 0; it < NSAMP; ++it) {
      if (t == 0) {
        out_lds[it * 3 + 0] = cx;
        out_lds[it * 3 + 1] = cy;
        out_lds[it * 3 + 2] = cz;
      }

      float bv = -1.0f;
      #pragma unroll
      for (int r = 0; r < 16; ++r) {
        float dx = px[r] - cx;
        float dy = py[r] - cy;
        float dz = pz[r] - cz;
        float d  = fmaf(dz, dz, fmaf(dy, dy, dx * dx));  // scan-fused rounding
        float nd = fminf(dist[r], d);
        dist[r] = nd;
        bv = fmaxf(bv, nd);
      }
      int bi = t * 16 + 15;
      #pragma unroll
      for (int r = 14; r >= 0; --r) bi = (dist[r] == bv) ? (t * 16 + r) : bi;

      float rmax = bv;
      DPP_MAXSTEP(rmax, 0x111);
      DPP_MAXSTEP(rmax, 0x112);
      DPP_MAXSTEP(rmax, 0x114);
      DPP_MAXSTEP(rmax, 0x118);
      DPP_MAXSTEP(rmax, 0x142);
      DPP_MAXSTEP(rmax, 0x143);
      float vmax = __int_as_float(
          __builtin_amdgcn_readlane(__float_as_int(rmax), 63));

      unsigned long long m = __ballot(bv == vmax);
      int L = __ffsll((long long)m) - 1;
      int widx = __builtin_amdgcn_readlane(bi, L);

      const int slot = it & 1;
      if (lane == 0) part[slot][wv] = make_uint2(__float_as_uint(vmax), (unsigned)widx);
      __syncthreads();

      const uint4* pp = (const uint4*)&part[slot][0];
      uint4 p0 = pp[0], p1 = pp[1], p2 = pp[2], p3 = pp[3];
      float v = __uint_as_float(p0.x); unsigned f = p0.y;
      float w1v = __uint_as_float(p0.z);
      if (w1v > v) { v = w1v; f = p0.w; }
      float w2v = __uint_as_float(p1.x);
      if (w2v > v) { v = w2v; f = p1.y; }
      float w3v = __uint_as_float(p1.z);
      if (w3v > v) { v = w3v; f = p1.w; }
      float w4v = __uint_as_float(p2.x);
      if (w4v > v) { v = w4v; f = p2.y; }
      float w5v = __uint_as_float(p2.z);
      if (w5v > v) { v = w5v; f = p2.w; }
      float w6v = __uint_as_float(p3.x);
      if (w6v > v) { v = w6v; f = p3.y; }
      float w7v = __uint_as_float(p3.z);
      if (w7v > v) { v = w7v; f = p3.w; }

      cx = bx[f * 3 + 0];
      cy = bx[f * 3 + 1];
      cz = bx[f * 3 + 2];

      // chunk publish: 64 centroids -> global + RELEASE progress bump
      if ((it & 63) == 63) {
        const int c = it >> 6;
        if (t < 192) {
          float* ob = out_sampled + (size_t)b * NSAMP * 3;
          ob[c * 192 + t] = out_lds[c * 192 + t];
        }
        __syncthreads();   // drain chunk stores (vmcnt) before release
        if (t == 0)
          __hip_atomic_fetch_add(&ctrl[1 + b], 64u, __ATOMIC_RELEASE,
                                 __HIP_MEMORY_SCOPE_AGENT);
      }
    }
    return;
  }

  // ================= Worker =================
  __shared__ __align__(16) unsigned short fT[32][104];   // feats bf16 K=96+8
  __shared__ __align__(16) unsigned short h1c[32][72];   // K=64+8
  __shared__ __align__(16) unsigned short h2c[32][136];  // K=128+8
  __shared__ float pmax[8][256];
  __shared__ int   sidx[32];
  __shared__ float s_c[4];
  __shared__ int   s_task;

  const int w    = t >> 6;
  const int lane = t & 63;
  const int quad = lane >> 4;
  const int ncol = lane & 15;

  for (;;) {
    if (t == 0) s_task = (int)atomicAdd(&ctrl[0], 1u);
    __syncthreads();
    const int task = s_task;
    if (task >= NTASK) break;
    const int b = task & 15, idx = task >> 4;   // round-robin batches

    if (t == 0) {
      while ((int)__hip_atomic_load(&ctrl[1 + b], __ATOMIC_RELAXED,
                                    __HIP_MEMORY_SCOPE_AGENT) <= idx)
        __builtin_amdgcn_s_sleep(8);
      (void)__hip_atomic_load(&ctrl[1 + b], __ATOMIC_ACQUIRE,
                              __HIP_MEMORY_SCOPE_AGENT);  // invalidate L1/L2
      const float* cp = out_sampled + ((size_t)b * NSAMP + idx) * 3;
      s_c[0] = cp[0]; s_c[1] = cp[1]; s_c[2] = cp[2];
    }
    __syncthreads();

    // ball query — wave 0, EAGER reference rounding (bit-exact, DO NOT TOUCH)
    if (w == 0) {
      const float R2 = (float)(0.2 * 0.2);
      float cx = s_c[0], cy = s_c[1], cz = s_c[2];
      float na = ((cx * cx) + (cy * cy)) + (cz * cz);   // eager: plain adds
      const float* bx = xyz + (size_t)b * N_PTS * 3;
      int cnt = 0, first = 0;
      for (int base = 0; base < N_PTS && cnt < NGRP; base += 64) {
        int p = base + lane;
        float x = bx[p * 3 + 0];
        float y = bx[p * 3 + 1];
        float z = bx[p * 3 + 2];
        float nb  = ((x * x) + (y * y)) + (z * z);      // eager: plain adds
        float dot = fmaf(cz, z, fmaf(cy, y, cx * x));   // Eigen fma chain
        float sq  = (na + nb) - (2.0f * dot);
        bool inr = !(sq > R2);
        unsigned long long mm = __ballot(inr);
        if (cnt == 0 && mm != 0ull) first = base + (__ffsll((long long)mm) - 1);
        int before = __popcll(mm & ((1ull << lane) - 1ull));
        int pos = cnt + before;
        if (inr && pos < NGRP) sidx[pos] = p;
        cnt += __popcll(mm);
      }
      if (cnt < NGRP) { int q = cnt + lane; if (q < NGRP) sidx[q] = first; }
    }
    __syncthreads();

    // gather: rel(3) ++ fea(64) -> bf16 fT[pt][c], zero pad c in [67,96)
    {
      const int pt = t >> 4, c0 = t & 15;
      const int p = sidx[pt];
      const float* xp = xyz + ((size_t)b * N_PTS + p) * 3;
      const float* fp = fea + ((size_t)b * N_PTS + p) * 64;
      #pragma unroll
      for (int c = c0; c < 96; c += 16) {
        float v = (c < 3) ? (xp[c] - s_c[c]) : (c < 67 ? fp[c - 3] : 0.0f);
        fT[pt][c] = f2bf(v);
      }
    }
    __syncthreads();

    // layer 1: 8 tiles (2m x 4n), 1/wave; K: 3 steps
    {
      const int mt = w & 1, nt = w >> 1;
      float bb = b1[nt * 16 + ncol];
      f32x4 acc = {bb, bb, bb, bb};
      #pragma unroll
      for (int ks = 0; ks < 3; ++ks) {
        bf16x8 a = *(const bf16x8*)&fT[mt * 16 + ncol][ks * 32 + quad * 8];
        bf16x8 bf = *(const bf16x8*)(wf1 + ((size_t)(nt * 3 + ks) * 64 + lane) * 8);
        acc = __builtin_amdgcn_mfma_f32_16x16x32_bf16(a, bf, acc, 0, 0, 0);
      }
      #pragma unroll
      for (int r = 0; r < 4; ++r)
        h1c[mt * 16 + quad * 4 + r][nt * 16 + ncol] = f2bf(fmaxf(acc[r], 0.0f));
    }
    __syncthreads();

    // layer 2: 16 tiles (2m x 8n), 2/wave; K: 2 steps
    #pragma unroll
    for (int q2 = 0; q2 < 2; ++q2) {
      const int tid = w * 2 + q2, mt = tid & 1, nt = tid >> 1;
      float bb = b2[nt * 16 + ncol];
      f32x4 acc = {bb, bb, bb, bb};
      #pragma unroll
      for (int ks = 0; ks < 2; ++ks) {
        bf16x8 a = *(const bf16x8*)&h1c[mt * 16 + ncol][ks * 32 + quad * 8];
        bf16x8 bf = *(const bf16x8*)(wf2 + ((size_t)(nt * 2 + ks) * 64 + lane) * 8);
        acc = __builtin_amdgcn_mfma_f32_16x16x32_bf16(a, bf, acc, 0, 0, 0);
      }
      #pragma unroll
      for (int r = 0; r < 4; ++r)
        h2c[mt * 16 + quad * 4 + r][nt * 16 + ncol] = f2bf(fmaxf(acc[r], 0.0f));
    }
    __syncthreads();

    // layer 3 + pool: 32 tiles (2m x 16n), 4/wave; K: 4 steps
    #pragma unroll
    for (int q2 = 0; q2 < 4; ++q2) {
      const int tid = w * 4 + q2, mt = tid & 1, nt = tid >> 1;
      float bb = b3[nt * 16 + ncol];
      f32x4 acc = {bb, bb, bb, bb};
      #pragma unroll
      for (int ks = 0; ks < 4; ++ks) {
        bf16x8 a = *(const bf16x8*)&h2c[mt * 16 + ncol][ks * 32 + quad * 8];
        bf16x8 bf = *(const bf16x8*)(wf3 + ((size_t)(nt * 4 + ks) * 64 + lane) * 8);
        acc = __builtin_amdgcn_mfma_f32_16x16x32_bf16(a, bf, acc, 0, 0, 0);
      }
      float mx = fmaxf(fmaxf(acc[0], acc[1]), fmaxf(acc[2], acc[3]));
      pmax[mt * 4 + quad][nt * 16 + ncol] = mx;
    }
    __syncthreads();

    if (t < 256) {
      float v = pmax[0][t];
      #pragma unroll
      for (int s = 1; s < 8; ++s) v = fmaxf(v, pmax[s][t]);
      out_mlp[((size_t)task) * 0 + ((size_t)((b << 10) + idx)) * 256 + t] =
          fmaxf(v, 0.0f);   // relu(max) == max(relu)
    }
    __syncthreads();   // protect LDS reuse across tasks
  }
}

// ---------------------------------------------------------------------------
extern "C" void kernel_launch(void* const* d_in, const int* in_sizes, int n_in,
                              void* d_out, int out_size, void* d_ws, size_t ws_size,
                              hipStream_t stream) {
  const float* xyz = (const float*)d_in[0];
  const float* fea = (const float*)d_in[1];
  const float* W1  = (const float*)d_in[2];
  const float* b1  = (const float*)d_in[3];
  const float* W2  = (const float*)d_in[4];
  const float* b2  = (const float*)d_in[5];
  const float* W3  = (const float*)d_in[6];
  const float* b3  = (const float*)d_in[7];

  float* outp    = (float*)d_out;
  float* sampled = outp;                    // output 0: (16,1024,3)
  float* mlp_out = outp + 16 * 1024 * 3;    // output 1: (16,1024,256)

  unsigned* ctrl = (unsigned*)d_ws;         // [0]=queue, [1..16]=progress
  unsigned short* wf1 = (unsigned short*)((char*)d_ws + 256);
  unsigned short* wf2 = wf1 + (size_t)12 * 64 * 8;
  unsigned short* wf3 = wf2 + (size_t)16 * 64 * 8;

  hipMemsetAsync(ctrl, 0, 256, stream);
  prep_w_kernel<<<23, 256, 0, stream>>>(W1, W2, W3, wf1, wf2, wf3);
  fused_kernel<<<256, 512, 0, stream>>>(xyz, fea, sampled, mlp_out,
                                        wf1, wf2, wf3, b1, b2, b3, ctrl);
}